// Round 10
// baseline (14693.423 us; speedup 1.0000x reference)
//
#include <hip/hip_runtime.h>
#include <math.h>

#define NSTATES 1024
#define TT      4096
#define DD      20

#define FW_BLOCKS  64
#define FW_THREADS 256
#define JPB  16      // j per block   (FW_BLOCKS * JPB = NSTATES)
#define NSEG 16      // k segments    (JPB * NSEG = FW_THREADS)
#define KSEG 64      // k per segment (NSEG * KSEG = NSTATES)

#define SENT 0x7FC00000u   // canonical NaN: computed column values are never NaN

// workspace layout (bytes)
#define OFF_LAT   ((size_t)0)               // 4 MB  logA transposed: lat[j*N+k] = log(trans[k][j])
#define OFF_COLS  ((size_t)20 << 20)        // 16 MB per-step columns cols[t*N+j]
#define OFF_PTR   ((size_t)36 << 20)        // 8 MB  u16 backpointers, rows 1..T-1

typedef unsigned int u32;

__global__ void k_init(uint4* __restrict__ cols4) {
    // fill 16 MB of cols with the sentinel (4M words = 1M uint4)
    int id = blockIdx.x * 256 + threadIdx.x;
    cols4[id] = make_uint4(SENT, SENT, SENT, SENT);
}

__global__ void k_logtrans(const float* __restrict__ tr, float* __restrict__ lat) {
    int id = blockIdx.x * 256 + threadIdx.x;        // 1M threads
    int k = id >> 10, j = id & 1023;
    lat[(size_t)j * NSTATES + k] = logf(tr[id]);    // coalesced read, strided write (one-time)
}

// Forward pass: R3/R7 handoff protocol byte-for-byte (verified local optimum
// across 4 failed protocol attacks). Emission fused (R9) but with the d-sum
// moved OFF the critical chain: the publisher thread (tid<16) computes its
// j's full 20-d emission sum IN REGISTERS, PRE-POLL (R9 proved pre-poll work
// hides in the ~2us poll dead time; its publisher-side LDS d-sum cost
// +170cy/step 1:1 -- that is what this round removes). Post-barrier-2 chain
// returns to R3's exact shape + one register add.
__global__ __launch_bounds__(FW_THREADS, 1) void k_forward(
    const float* __restrict__ lat, const float* __restrict__ ev,
    const float* __restrict__ epar, const float* __restrict__ prior,
    float* __restrict__ cols, unsigned short* __restrict__ bptr)
{
    // padded [16][68]: row r holds words [r*64, r*64+64) of the prev column.
    __shared__ __align__(16) float prevs[NSEG * 68];
    __shared__ float          smaxw[4][JPB];   // per-wave partials (segs 4w..4w+3)
    __shared__ unsigned short sidxw[4][JPB];
    const int tid  = threadIdx.x;
    const int seg  = tid >> 4;                  // 0..15: k in [seg*64, seg*64+64)
    const int jj   = tid & (JPB - 1);
    const int wav  = tid >> 6;                  // wave id 0..3 (holds segs 4w..4w+3)
    const int j0   = blockIdx.x * JPB;
    const int j    = j0 + jj;
    const float lat00 = lat[0];                 // log trans[0][0], for the j==0 quirk

    // ---- publisher-only emission constants, register-resident (static
    // indexing via full unroll -> no scratch). Computed once; coef/den
    // bit-identical to the verified k_emis prologue.
    float em_m[DD], em_cf[DD], em_dn[DD];
    if (tid < JPB) {
        const float* ep = epar + (size_t)(j0 + tid) * (2 * DD);
        #pragma unroll
        for (int d = 0; d < DD; ++d) {
            float m = ep[2 * d];
            float s = ep[2 * d + 1];
            float tp = 6.2831853071795864769f * s;
            em_m[d]  = m;
            em_cf[d] = 1.0f / sqrtf(tp);
            em_dn[d] = 2.0f * (s * s);
        }
    }
    // faithful to reference: p = coef * expf(-num/den); acc += logf(p),
    // ascending d (same serial order as the verified k_emis => bit-identical).
    auto esum_at = [&](int t) -> float {
        const float* x = ev + (size_t)t * DD;
        float xr[DD];
        #pragma unroll
        for (int u = 0; u < 5; ++u) {
            float4 v = *(const float4*)(x + 4 * u);
            xr[4 * u + 0] = v.x; xr[4 * u + 1] = v.y;
            xr[4 * u + 2] = v.z; xr[4 * u + 3] = v.w;
        }
        float acc = 0.0f;
        #pragma unroll
        for (int d = 0; d < DD; ++d) {
            float df  = xr[d] - em_m[d];
            float num = df * df;
            float p   = em_cf[d] * expf(-num / em_dn[d]);
            acc += logf(p);                     // -inf propagates; never NaN
        }
        return acc;
    };

    // ---- t = 0: publish col0 FIRST (before latr preload) so downstream
    // blocks' t=1 polls are satisfied as early as possible.
    if (tid < JPB) {
        float c0 = logf(prior[j0 + tid]) + esum_at(0);
        __hip_atomic_store((u32*)cols + (j0 + tid), __float_as_uint(c0),
                           __ATOMIC_RELAXED, __HIP_MEMORY_SCOPE_AGENT);
    }

    // preload this thread's lat slice into registers (loop-invariant)
    float4 latr[16];
    {
        const float* lrow = lat + (size_t)j * NSTATES + seg * KSEG;
        #pragma unroll
        for (int u = 0; u < 16; ++u) latr[u] = *(const float4*)(lrow + u * 4);
    }

    // thread stages its 4 polled words at padded (row tid>>4, col (tid&15)*4)
    float* dstp = &prevs[(tid >> 4) * 68 + (tid & 15) * 4];
    const float* rowp = &prevs[seg * 68];

    for (int t = 1; t < TT; ++t) {
        // publisher computes this step's emission sum pre-poll (dead time)
        float esum = 0.0f;
        if (tid < JPB) esum = esum_at(t);

        // ---- poll previous column: 4 relaxed agent-scope word loads/thread,
        // per-thread exit (the proven protocol).
        const u32* p = (const u32*)(cols + (size_t)(t - 1) * NSTATES) + tid * 4;
        u32 w0, w1, w2, w3;
        for (;;) {
            w0 = __hip_atomic_load(p + 0, __ATOMIC_RELAXED, __HIP_MEMORY_SCOPE_AGENT);
            w1 = __hip_atomic_load(p + 1, __ATOMIC_RELAXED, __HIP_MEMORY_SCOPE_AGENT);
            w2 = __hip_atomic_load(p + 2, __ATOMIC_RELAXED, __HIP_MEMORY_SCOPE_AGENT);
            w3 = __hip_atomic_load(p + 3, __ATOMIC_RELAXED, __HIP_MEMORY_SCOPE_AGENT);
            if (w0 != SENT && w1 != SENT && w2 != SENT && w3 != SENT) break;
            __builtin_amdgcn_s_sleep(1);
        }
        {
            float4 v;
            v.x = __uint_as_float(w0);
            v.y = __uint_as_float(w1);
            v.z = __uint_as_float(w2);
            v.w = __uint_as_float(w3);
            *(float4*)dstp = v;                 // padded b128 store, conflict-free
        }
        __syncthreads();                        // barrier 1: staging visible to all

        // ---- scan this thread's 64 k's for its j: first-max (strict >, asc k)
        float best = -__builtin_inff();
        int bidx = seg * KSEG;
        #pragma unroll
        for (int u = 0; u < 16; ++u) {
            float4 q  = *(const float4*)(rowp + u * 4);   // 16-lane broadcast
            float4 wv = latr[u];
            int k0 = seg * KSEG + u * 4;
            float v0 = q.x + wv.x;
            float v1 = q.y + wv.y;
            float v2 = q.z + wv.z;
            float v3 = q.w + wv.w;
            if (v0 > best) { best = v0; bidx = k0;     }
            if (v1 > best) { best = v1; bidx = k0 + 1; }
            if (v2 > best) { best = v2; bidx = k0 + 2; }
            if (v3 > best) { best = v3; bidx = k0 + 3; }
        }

        // ---- combine the wave's 4 segs per j via shfl (disjoint ascending k
        // ranges: tie -> smaller bidx == sequential first-max). No sync.
        {
            float ov = __shfl_xor(best, 16);
            int   oi = __shfl_xor(bidx, 16);
            if (ov > best || (ov == best && oi < bidx)) { best = ov; bidx = oi; }
            ov = __shfl_xor(best, 32);
            oi = __shfl_xor(bidx, 32);
            if (ov > best || (ov == best && oi < bidx)) { best = ov; bidx = oi; }
        }
        if ((tid & 63) < JPB) {                 // one lane per (wave, jj)
            smaxw[wav][jj] = best;
            sidxw[wav][jj] = (unsigned short)bidx;
        }
        __syncthreads();                        // barrier 2: partials visible

        // ---- final 4-deep combine (ascending wave == ascending seg) + publish
        if (tid < JPB) {
            float m = smaxw[0][tid];
            int  mi = sidxw[0][tid];
            #pragma unroll
            for (int ww = 1; ww < 4; ++ww) {
                float v = smaxw[ww][tid];
                if (v > m) { m = v; mi = sidxw[ww][tid]; }
            }
            int jw = j0 + tid;
            // reference quirk: j==0 forced from state 0; prevs[0] (staged by
            // tid 0, wave 0 -- not yet overwritten) is cols[t-1][0].
            float val = (jw == 0) ? (prevs[0] + lat00) : m;
            float out = val + esum;             // one register add -- R3 chain
            __hip_atomic_store((u32*)(cols + (size_t)t * NSTATES) + jw,
                               __float_as_uint(out), __ATOMIC_RELAXED,
                               __HIP_MEMORY_SCOPE_AGENT);
            bptr[(size_t)t * NSTATES + jw] = (unsigned short)mi;
        }
        // no third barrier: next iteration's staging only overwrites prevs rows
        // whose readers (scans) completed before barrier 2; smaxw reuse is
        // ordered by the next iteration's barrier 1.
    }
}

// Double-buffered backtrace (verified in rounds 6-9): 255 threads stage
// chunk c+1 from HBM while lane 0 chases chunk c through LDS.
#define BTC 16  // ptr rows per LDS chunk; 2 buffers x 16 rows x 2KB = 64 KB
__global__ void k_backtrace(const float* __restrict__ lastcol,
                            const unsigned short* __restrict__ bptr,
                            int* __restrict__ seq)
{
    __shared__ unsigned short ring[2][BTC][NSTATES];
    __shared__ int s_front;
    const int tid = threadIdx.x;    // 256 threads

    // last = first-max argmax over final column (wave 0)
    if (tid < 64) {
        float best = -__builtin_inff();
        int bi = 0;
        for (int n2 = tid; n2 < NSTATES; n2 += 64) {
            float v = lastcol[n2];
            if (v > best) { best = v; bi = n2; }
        }
        #pragma unroll
        for (int off = 32; off > 0; off >>= 1) {
            float ov = __shfl_xor(best, off);
            int   oi = __shfl_xor(bi, off);
            if (ov > best || (ov == best && oi < bi)) { best = ov; bi = oi; }
        }
        if (tid == 0) { seq[TT] = bi; seq[TT - 1] = bi; s_front = bi; }
    }
    __syncthreads();

    // chunks descend: chunk c covers rows rhi=TT-1-c*BTC .. max(rhi-BTC+1, 1).
    auto stage = [&](int c, int buf, int t0, int stride) {
        int rhi = TT - 1 - c * BTC;
        int rlo = rhi - (BTC - 1); if (rlo < 1) rlo = 1;
        int n4 = (rhi - rlo + 1) * 128;                 // uint4 per chunk
        uint4* dst = (uint4*)&ring[buf][0][0];
        for (int idx = t0; idx < n4; idx += stride) {
            int ro = idx >> 7, wo = idx & 127;
            dst[idx] = ((const uint4*)(bptr + (size_t)(rhi - ro) * NSTATES))[wo];
        }
    };
    const int nc = (TT - 1 + BTC - 1) / BTC;            // 256
    stage(0, 0, tid, 256);
    __syncthreads();
    for (int c = 0; c < nc; ++c) {
        int buf = c & 1;
        if (tid != 0) {
            if (c + 1 < nc) stage(c + 1, buf ^ 1, tid - 1, 255);
        } else {
            int rhi = TT - 1 - c * BTC;
            int rlo = rhi - (BTC - 1); if (rlo < 1) rlo = 1;
            int front = s_front;
            for (int r = rhi; r >= rlo; --r) {
                front = (int)ring[buf][rhi - r][front];
                seq[r - 1] = front;
            }
            s_front = front;
        }
        __syncthreads();
    }
}

extern "C" void kernel_launch(void* const* d_in, const int* in_sizes, int n_in,
                              void* d_out, int out_size, void* d_ws, size_t ws_size,
                              hipStream_t stream) {
    const float* ev    = (const float*)d_in[0];   // [T, D]
    const float* prior = (const float*)d_in[1];   // [N]
    const float* tr    = (const float*)d_in[2];   // [N, N]
    const float* epar  = (const float*)d_in[3];   // [N, D, 2]
    int* seq = (int*)d_out;                       // [T+1]
    char* ws = (char*)d_ws;
    float* lat  = (float*)(ws + OFF_LAT);
    float* cols = (float*)(ws + OFF_COLS);
    unsigned short* bptr = (unsigned short*)(ws + OFF_PTR);

    k_init<<<4096, 256, 0, stream>>>((uint4*)cols);              // sentinel-fill 16 MB
    k_logtrans<<<4096, 256, 0, stream>>>(tr, lat);
    k_forward<<<FW_BLOCKS, FW_THREADS, 0, stream>>>(lat, ev, epar, prior, cols, bptr);
    k_backtrace<<<1, 256, 0, stream>>>(cols + (size_t)(TT - 1) * NSTATES, bptr, seq);
}

// Round 11
// 9682.268 us; speedup vs baseline: 1.5176x; 1.5176x over previous
//
#include <hip/hip_runtime.h>
#include <math.h>

#define NSTATES 1024
#define TT      4096
#define DD      20

#define FW_BLOCKS  64
#define FW_THREADS 256
#define JPB  16      // j per block   (FW_BLOCKS * JPB = NSTATES)
#define NSEG 16      // k segments    (JPB * NSEG = FW_THREADS)
#define KSEG 64      // k per segment (NSEG * KSEG = NSTATES)

#define SENT 0x7FC00000u   // canonical NaN: computed column values are never NaN

// workspace layout (bytes)
#define OFF_LAT   ((size_t)0)               // 4 MB  logA transposed: lat[j*N+k] = log(trans[k][j])
#define OFF_COLS  ((size_t)20 << 20)        // 16 MB per-step columns cols[t*N+j]
#define OFF_PTR   ((size_t)36 << 20)        // 8 MB  u16 backpointers, rows 1..T-1

typedef unsigned int u32;

__global__ void k_init(uint4* __restrict__ cols4) {
    // fill 16 MB of cols with the sentinel (4M words = 1M uint4)
    int id = blockIdx.x * 256 + threadIdx.x;
    cols4[id] = make_uint4(SENT, SENT, SENT, SENT);
}

__global__ void k_logtrans(const float* __restrict__ tr, float* __restrict__ lat) {
    int id = blockIdx.x * 256 + threadIdx.x;        // 1M threads
    int k = id >> 10, j = id & 1023;
    lat[(size_t)j * NSTATES + k] = logf(tr[id]);    // coalesced read, strided write (one-time)
}

// Forward pass: R3/R7 handoff protocol byte-for-byte. Emission fused with the
// measured-correct placement:
//   - emis distributed over 256 threads (R9: hides pre/post-poll, ~4 insts/thd)
//   - the publisher's serial 20-d sum runs in the POST-PUBLISH shadow for
//     step t+1 (R3 ablation: work there is invisible), leaving the
//     post-barrier-2 critical chain = R3 + one register add.
//   - R10's mistake (whole slice on 16 lanes of the publishing wave: +2300cy
//     on the period) is reverted.
__global__ __launch_bounds__(FW_THREADS, 1) void k_forward(
    const float* __restrict__ lat, const float* __restrict__ ev,
    const float* __restrict__ epar, const float* __restrict__ prior,
    float* __restrict__ cols, unsigned short* __restrict__ bptr)
{
    // padded [16][68]: row r holds words [r*64, r*64+64) of the prev column.
    __shared__ __align__(16) float prevs[NSEG * 68];
    __shared__ float          smaxw[4][JPB];   // per-wave partials (segs 4w..4w+3)
    __shared__ unsigned short sidxw[4][JPB];
    __shared__ float          elp[2][JPB][DD]; // double-buffered emission log-p
    const int tid  = threadIdx.x;
    const int seg  = tid >> 4;                  // 0..15: k in [seg*64, seg*64+64)
    const int jj   = tid & (JPB - 1);
    const int wav  = tid >> 6;                  // wave id 0..3 (holds segs 4w..4w+3)
    const int j0   = blockIdx.x * JPB;
    const int j    = j0 + jj;
    const float lat00 = lat[0];                 // log trans[0][0], for the j==0 quirk

    // ---- distributed-emission constants (items: it0 = tid, it1 = tid+256);
    // item -> (jj_e = item/20, d_e = item%20); 320 items cover 16j x 20d.
    const int jj0e = tid / DD, d0e = tid % DD;
    const float m0 = epar[((size_t)(j0 + jj0e) * DD + d0e) * 2 + 0];
    const float s0 = epar[((size_t)(j0 + jj0e) * DD + d0e) * 2 + 1];
    const float coef0 = 1.0f / sqrtf(6.2831853071795864769f * s0);
    const float den0  = 2.0f * (s0 * s0);
    const bool  has1  = (tid + 256) < JPB * DD;     // tid < 64
    const int   it1   = tid + 256;
    const int jj1e = has1 ? it1 / DD : 0, d1e = has1 ? it1 % DD : 0;
    const float m1 = has1 ? epar[((size_t)(j0 + jj1e) * DD + d1e) * 2 + 0] : 0.0f;
    const float s1 = has1 ? epar[((size_t)(j0 + jj1e) * DD + d1e) * 2 + 1] : 1.0f;
    const float coef1 = 1.0f / sqrtf(6.2831853071795864769f * s1);
    const float den1  = 2.0f * (s1 * s1);

    // faithful to reference: p = coef * expf(-num/den); logp = logf(p).
    // -inf (underflow) propagates; never NaN. Verbatim from the verified k_emis.
    auto emis = [&](int t, int buf) {
        float x0  = ev[(size_t)t * DD + d0e];
        float df0 = x0 - m0;
        float num0 = df0 * df0;
        float p0  = coef0 * expf(-num0 / den0);
        elp[buf][jj0e][d0e] = logf(p0);
        if (has1) {
            float x1  = ev[(size_t)t * DD + d1e];
            float df1 = x1 - m1;
            float num1 = df1 * df1;
            float p1  = coef1 * expf(-num1 / den1);
            elp[buf][jj1e][d1e] = logf(p1);
        }
    };

    // preload this thread's lat slice into registers (loop-invariant)
    float4 latr[16];
    {
        const float* lrow = lat + (size_t)j * NSTATES + seg * KSEG;
        #pragma unroll
        for (int u = 0; u < 16; ++u) latr[u] = *(const float4*)(lrow + u * 4);
    }

    // thread stages its 4 polled words at padded (row tid>>4, col (tid&15)*4)
    float* dstp = &prevs[(tid >> 4) * 68 + (tid & 15) * 4];
    const float* rowp = &prevs[seg * 68];

    // ---- prologue: col0 (t=0) and the pipelined esum for t=1 ----
    emis(0, 0);
    __syncthreads();
    if (tid < JPB) {
        float acc = 0.0f;
        #pragma unroll
        for (int d = 0; d < DD; ++d) acc += elp[0][tid][d];   // ascending d
        float c0 = logf(prior[j0 + tid]) + acc;
        __hip_atomic_store((u32*)cols + (j0 + tid), __float_as_uint(c0),
                           __ATOMIC_RELAXED, __HIP_MEMORY_SCOPE_AGENT);
    }
    __syncthreads();                            // col0 sum read before buf reuse
    emis(1, 1);
    __syncthreads();
    float esum_reg = 0.0f;
    if (tid < JPB) {
        #pragma unroll
        for (int d = 0; d < DD; ++d) esum_reg += elp[1][tid][d];   // ascending d
    }

    for (int t = 1; t < TT; ++t) {
        // ---- poll previous column: 4 relaxed agent-scope word loads/thread,
        // per-thread exit (the proven protocol).
        const u32* p = (const u32*)(cols + (size_t)(t - 1) * NSTATES) + tid * 4;
        u32 w0, w1, w2, w3;
        for (;;) {
            w0 = __hip_atomic_load(p + 0, __ATOMIC_RELAXED, __HIP_MEMORY_SCOPE_AGENT);
            w1 = __hip_atomic_load(p + 1, __ATOMIC_RELAXED, __HIP_MEMORY_SCOPE_AGENT);
            w2 = __hip_atomic_load(p + 2, __ATOMIC_RELAXED, __HIP_MEMORY_SCOPE_AGENT);
            w3 = __hip_atomic_load(p + 3, __ATOMIC_RELAXED, __HIP_MEMORY_SCOPE_AGENT);
            if (w0 != SENT && w1 != SENT && w2 != SENT && w3 != SENT) break;
            __builtin_amdgcn_s_sleep(1);
        }
        {
            float4 v;
            v.x = __uint_as_float(w0);
            v.y = __uint_as_float(w1);
            v.z = __uint_as_float(w2);
            v.w = __uint_as_float(w3);
            *(float4*)dstp = v;                 // padded b128 store, conflict-free
        }
        __syncthreads();                        // barrier 1: staging visible to all

        // ---- scan this thread's 64 k's for its j: first-max (strict >, asc k)
        float best = -__builtin_inff();
        int bidx = seg * KSEG;
        #pragma unroll
        for (int u = 0; u < 16; ++u) {
            float4 q  = *(const float4*)(rowp + u * 4);   // 16-lane broadcast
            float4 wv = latr[u];
            int k0 = seg * KSEG + u * 4;
            float v0 = q.x + wv.x;
            float v1 = q.y + wv.y;
            float v2 = q.z + wv.z;
            float v3 = q.w + wv.w;
            if (v0 > best) { best = v0; bidx = k0;     }
            if (v1 > best) { best = v1; bidx = k0 + 1; }
            if (v2 > best) { best = v2; bidx = k0 + 2; }
            if (v3 > best) { best = v3; bidx = k0 + 3; }
        }

        // ---- combine the wave's 4 segs per j via shfl (disjoint ascending k
        // ranges: tie -> smaller bidx == sequential first-max). No sync.
        {
            float ov = __shfl_xor(best, 16);
            int   oi = __shfl_xor(bidx, 16);
            if (ov > best || (ov == best && oi < bidx)) { best = ov; bidx = oi; }
            ov = __shfl_xor(best, 32);
            oi = __shfl_xor(bidx, 32);
            if (ov > best || (ov == best && oi < bidx)) { best = ov; bidx = oi; }
        }
        if ((tid & 63) < JPB) {                 // one lane per (wave, jj)
            smaxw[wav][jj] = best;
            sidxw[wav][jj] = (unsigned short)bidx;
        }
        __syncthreads();                        // barrier 2: partials visible

        // ---- final 4-deep combine (ascending wave == ascending seg) + publish
        if (tid < JPB) {
            float m = smaxw[0][tid];
            int  mi = sidxw[0][tid];
            #pragma unroll
            for (int ww = 1; ww < 4; ++ww) {
                float v = smaxw[ww][tid];
                if (v > m) { m = v; mi = sidxw[ww][tid]; }
            }
            int jw = j0 + tid;
            // reference quirk: j==0 forced from state 0; prevs[0] (staged by
            // tid 0, wave 0 -- not yet overwritten) is cols[t-1][0].
            float val = (jw == 0) ? (prevs[0] + lat00) : m;
            float out = val + esum_reg;         // one register add -- R3 chain
            __hip_atomic_store((u32*)(cols + (size_t)t * NSTATES) + jw,
                               __float_as_uint(out), __ATOMIC_RELAXED,
                               __HIP_MEMORY_SCOPE_AGENT);
            bptr[(size_t)t * NSTATES + jw] = (unsigned short)mi;
        }

        // ---- post-publish shadow: compute step t+1's emission slice and its
        // serial d-sum (ascending d, bit-order identical to all passing
        // rounds). Sits entirely in the ~2us poll slack before t+1's column
        // completes. Buffer (t+1)&1 was last read at step t-1 (register sum),
        // strictly before barrier 1 of step t -> safe to overwrite.
        if (t + 1 < TT) {
            emis(t + 1, (t + 1) & 1);
            __syncthreads();                    // barrier 3 (in shadow)
            if (tid < JPB) {
                float acc = 0.0f;
                #pragma unroll
                for (int d = 0; d < DD; ++d) acc += elp[(t + 1) & 1][tid][d];
                esum_reg = acc;
            }
        }
        // no fourth barrier: next iteration's prevs staging only overwrites
        // rows whose readers completed before barrier 2; smaxw reuse is
        // ordered by the next iteration's barrier 1.
    }
}

// Double-buffered backtrace (verified in rounds 6-10): 255 threads stage
// chunk c+1 from HBM while lane 0 chases chunk c through LDS.
#define BTC 16  // ptr rows per LDS chunk; 2 buffers x 16 rows x 2KB = 64 KB
__global__ void k_backtrace(const float* __restrict__ lastcol,
                            const unsigned short* __restrict__ bptr,
                            int* __restrict__ seq)
{
    __shared__ unsigned short ring[2][BTC][NSTATES];
    __shared__ int s_front;
    const int tid = threadIdx.x;    // 256 threads

    // last = first-max argmax over final column (wave 0)
    if (tid < 64) {
        float best = -__builtin_inff();
        int bi = 0;
        for (int n2 = tid; n2 < NSTATES; n2 += 64) {
            float v = lastcol[n2];
            if (v > best) { best = v; bi = n2; }
        }
        #pragma unroll
        for (int off = 32; off > 0; off >>= 1) {
            float ov = __shfl_xor(best, off);
            int   oi = __shfl_xor(bi, off);
            if (ov > best || (ov == best && oi < bi)) { best = ov; bi = oi; }
        }
        if (tid == 0) { seq[TT] = bi; seq[TT - 1] = bi; s_front = bi; }
    }
    __syncthreads();

    // chunks descend: chunk c covers rows rhi=TT-1-c*BTC .. max(rhi-BTC+1, 1).
    auto stage = [&](int c, int buf, int t0, int stride) {
        int rhi = TT - 1 - c * BTC;
        int rlo = rhi - (BTC - 1); if (rlo < 1) rlo = 1;
        int n4 = (rhi - rlo + 1) * 128;                 // uint4 per chunk
        uint4* dst = (uint4*)&ring[buf][0][0];
        for (int idx = t0; idx < n4; idx += stride) {
            int ro = idx >> 7, wo = idx & 127;
            dst[idx] = ((const uint4*)(bptr + (size_t)(rhi - ro) * NSTATES))[wo];
        }
    };
    const int nc = (TT - 1 + BTC - 1) / BTC;            // 256
    stage(0, 0, tid, 256);
    __syncthreads();
    for (int c = 0; c < nc; ++c) {
        int buf = c & 1;
        if (tid != 0) {
            if (c + 1 < nc) stage(c + 1, buf ^ 1, tid - 1, 255);
        } else {
            int rhi = TT - 1 - c * BTC;
            int rlo = rhi - (BTC - 1); if (rlo < 1) rlo = 1;
            int front = s_front;
            for (int r = rhi; r >= rlo; --r) {
                front = (int)ring[buf][rhi - r][front];
                seq[r - 1] = front;
            }
            s_front = front;
        }
        __syncthreads();
    }
}

extern "C" void kernel_launch(void* const* d_in, const int* in_sizes, int n_in,
                              void* d_out, int out_size, void* d_ws, size_t ws_size,
                              hipStream_t stream) {
    const float* ev    = (const float*)d_in[0];   // [T, D]
    const float* prior = (const float*)d_in[1];   // [N]
    const float* tr    = (const float*)d_in[2];   // [N, N]
    const float* epar  = (const float*)d_in[3];   // [N, D, 2]
    int* seq = (int*)d_out;                       // [T+1]
    char* ws = (char*)d_ws;
    float* lat  = (float*)(ws + OFF_LAT);
    float* cols = (float*)(ws + OFF_COLS);
    unsigned short* bptr = (unsigned short*)(ws + OFF_PTR);

    k_init<<<4096, 256, 0, stream>>>((uint4*)cols);              // sentinel-fill 16 MB
    k_logtrans<<<4096, 256, 0, stream>>>(tr, lat);
    k_forward<<<FW_BLOCKS, FW_THREADS, 0, stream>>>(lat, ev, epar, prior, cols, bptr);
    k_backtrace<<<1, 256, 0, stream>>>(cols + (size_t)(TT - 1) * NSTATES, bptr, seq);
}

// Round 12
// 9451.870 us; speedup vs baseline: 1.5546x; 1.0244x over previous
//
#include <hip/hip_runtime.h>
#include <math.h>

#define NSTATES 1024
#define TT      4096
#define DD      20

#define FW_BLOCKS  64
#define FW_THREADS 256
#define JPB  16      // j per block   (FW_BLOCKS * JPB = NSTATES)
#define NSEG 16      // k segments    (JPB * NSEG = FW_THREADS)
#define KSEG 64      // k per segment (NSEG * KSEG = NSTATES)

#define SENT 0x7FC00000u   // canonical NaN: computed column values are never NaN

// workspace layout (bytes)
#define OFF_COLS  ((size_t)20 << 20)        // 16 MB per-step columns cols[t*N+j]
#define OFF_PTR   ((size_t)36 << 20)        // 8 MB  u16 backpointers, rows 1..T-1
// ready-counter: first word of bptr row 0 (dead row), zeroed by hipMemsetAsync.

typedef unsigned int u32;

#define ALD(p) __hip_atomic_load((p), __ATOMIC_RELAXED, __HIP_MEMORY_SCOPE_AGENT)

// Forward pass: R11 loop byte-for-byte (best measured: 8780 us dispatch,
// 2.14 us/step). NEW this round (prologue only):
//   - sentinel fill of cols fused in (each block fills its 256 KB slice)
//   - lat computed directly from tr into registers (same logf input order as
//     the old k_logtrans => bit-identical), no lat workspace at all
//   - grid-ready spin barrier (vmcnt-drained stores -> release add -> spin to
//     64; all 64 blocks resident and increment unconditionally => no deadlock)
// This removes two dispatches, the 4 MB lat round trip, and k_logtrans's
// 16x-amplified strided writes from the serial launch stream.
__global__ __launch_bounds__(FW_THREADS, 1) void k_forward(
    const float* __restrict__ tr, const float* __restrict__ ev,
    const float* __restrict__ epar, const float* __restrict__ prior,
    float* __restrict__ cols, unsigned short* __restrict__ bptr,
    u32* __restrict__ ready)
{
    // padded [16][68]: row r holds words [r*64, r*64+64) of the prev column.
    __shared__ __align__(16) float prevs[NSEG * 68];
    __shared__ float          smaxw[4][JPB];   // per-wave partials (segs 4w..4w+3)
    __shared__ unsigned short sidxw[4][JPB];
    __shared__ float          elp[2][JPB][DD]; // double-buffered emission log-p
    const int tid  = threadIdx.x;
    const int seg  = tid >> 4;                  // 0..15: k in [seg*64, seg*64+64)
    const int jj   = tid & (JPB - 1);
    const int wav  = tid >> 6;                  // wave id 0..3 (holds segs 4w..4w+3)
    const int j0   = blockIdx.x * JPB;
    const int j    = j0 + jj;

    // ---- prologue A: sentinel-fill this block's slice of cols (256 KB)
    {
        uint4* mine = (uint4*)cols + (size_t)blockIdx.x * (NSTATES * TT / 4 / FW_BLOCKS);
        const uint4 sv = make_uint4(SENT, SENT, SENT, SENT);
        #pragma unroll
        for (int i = 0; i < (NSTATES * TT / 4 / FW_BLOCKS) / FW_THREADS; ++i)
            mine[i * FW_THREADS + tid] = sv;
    }

    // ---- prologue B: lat slice direct from tr (bit-identical to k_logtrans:
    // same logf on the same tr element). lat[j*N+k] = logf(tr[k*N+j]).
    const float lat00 = logf(tr[0]);            // log trans[0][0] (j==0 quirk)
    float4 latr[16];
    #pragma unroll
    for (int u = 0; u < 16; ++u) {
        #pragma unroll
        for (int i = 0; i < 4; ++i) {
            int k = seg * KSEG + u * 4 + i;
            ((float*)&latr[u])[i] = logf(tr[(size_t)k * NSTATES + j]);
        }
    }

    // ---- distributed-emission constants (items: it0 = tid, it1 = tid+256);
    // item -> (jj_e = item/20, d_e = item%20); 320 items cover 16j x 20d.
    const int jj0e = tid / DD, d0e = tid % DD;
    const float m0 = epar[((size_t)(j0 + jj0e) * DD + d0e) * 2 + 0];
    const float s0 = epar[((size_t)(j0 + jj0e) * DD + d0e) * 2 + 1];
    const float coef0 = 1.0f / sqrtf(6.2831853071795864769f * s0);
    const float den0  = 2.0f * (s0 * s0);
    const bool  has1  = (tid + 256) < JPB * DD;     // tid < 64
    const int   it1   = tid + 256;
    const int jj1e = has1 ? it1 / DD : 0, d1e = has1 ? it1 % DD : 0;
    const float m1 = has1 ? epar[((size_t)(j0 + jj1e) * DD + d1e) * 2 + 0] : 0.0f;
    const float s1 = has1 ? epar[((size_t)(j0 + jj1e) * DD + d1e) * 2 + 1] : 1.0f;
    const float coef1 = 1.0f / sqrtf(6.2831853071795864769f * s1);
    const float den1  = 2.0f * (s1 * s1);

    // faithful to reference: p = coef * expf(-num/den); logp = logf(p).
    // -inf (underflow) propagates; never NaN. Verbatim from the verified k_emis.
    auto emis = [&](int t, int buf) {
        float x0  = ev[(size_t)t * DD + d0e];
        float df0 = x0 - m0;
        float num0 = df0 * df0;
        float p0  = coef0 * expf(-num0 / den0);
        elp[buf][jj0e][d0e] = logf(p0);
        if (has1) {
            float x1  = ev[(size_t)t * DD + d1e];
            float df1 = x1 - m1;
            float num1 = df1 * df1;
            float p1  = coef1 * expf(-num1 / den1);
            elp[buf][jj1e][d1e] = logf(p1);
        }
    };

    // ---- prologue C: grid-ready barrier. Drain fill stores to the LLC, then
    // count in; spin until all 64 blocks counted. Increment is unconditional
    // and precedes the spin => counter reaches 64 => no deadlock.
    __syncthreads();                            // block's fill issued by all
    if (tid == 0) {
        asm volatile("s_waitcnt vmcnt(0)" ::: "memory");   // fill visible first
        __hip_atomic_fetch_add(ready, 1u, __ATOMIC_RELEASE,
                               __HIP_MEMORY_SCOPE_AGENT);
        while (ALD(ready) < (u32)FW_BLOCKS) __builtin_amdgcn_s_sleep(2);
    }
    __syncthreads();                            // whole grid sentinel-ready

    // thread stages its 4 polled words at padded (row tid>>4, col (tid&15)*4)
    float* dstp = &prevs[(tid >> 4) * 68 + (tid & 15) * 4];
    const float* rowp = &prevs[seg * 68];

    // ---- prologue D: col0 (t=0) and the pipelined esum for t=1 ----
    emis(0, 0);
    __syncthreads();
    if (tid < JPB) {
        float acc = 0.0f;
        #pragma unroll
        for (int d = 0; d < DD; ++d) acc += elp[0][tid][d];   // ascending d
        float c0 = logf(prior[j0 + tid]) + acc;
        __hip_atomic_store((u32*)cols + (j0 + tid), __float_as_uint(c0),
                           __ATOMIC_RELAXED, __HIP_MEMORY_SCOPE_AGENT);
    }
    __syncthreads();                            // col0 sum read before buf reuse
    emis(1, 1);
    __syncthreads();
    float esum_reg = 0.0f;
    if (tid < JPB) {
        #pragma unroll
        for (int d = 0; d < DD; ++d) esum_reg += elp[1][tid][d];   // ascending d
    }

    for (int t = 1; t < TT; ++t) {
        // ---- poll previous column: 4 relaxed agent-scope word loads/thread,
        // per-thread exit (the proven protocol).
        const u32* p = (const u32*)(cols + (size_t)(t - 1) * NSTATES) + tid * 4;
        u32 w0, w1, w2, w3;
        for (;;) {
            w0 = __hip_atomic_load(p + 0, __ATOMIC_RELAXED, __HIP_MEMORY_SCOPE_AGENT);
            w1 = __hip_atomic_load(p + 1, __ATOMIC_RELAXED, __HIP_MEMORY_SCOPE_AGENT);
            w2 = __hip_atomic_load(p + 2, __ATOMIC_RELAXED, __HIP_MEMORY_SCOPE_AGENT);
            w3 = __hip_atomic_load(p + 3, __ATOMIC_RELAXED, __HIP_MEMORY_SCOPE_AGENT);
            if (w0 != SENT && w1 != SENT && w2 != SENT && w3 != SENT) break;
            __builtin_amdgcn_s_sleep(1);
        }
        {
            float4 v;
            v.x = __uint_as_float(w0);
            v.y = __uint_as_float(w1);
            v.z = __uint_as_float(w2);
            v.w = __uint_as_float(w3);
            *(float4*)dstp = v;                 // padded b128 store, conflict-free
        }
        __syncthreads();                        // barrier 1: staging visible to all

        // ---- scan this thread's 64 k's for its j: first-max (strict >, asc k)
        float best = -__builtin_inff();
        int bidx = seg * KSEG;
        #pragma unroll
        for (int u = 0; u < 16; ++u) {
            float4 q  = *(const float4*)(rowp + u * 4);   // 16-lane broadcast
            float4 wv = latr[u];
            int k0 = seg * KSEG + u * 4;
            float v0 = q.x + wv.x;
            float v1 = q.y + wv.y;
            float v2 = q.z + wv.z;
            float v3 = q.w + wv.w;
            if (v0 > best) { best = v0; bidx = k0;     }
            if (v1 > best) { best = v1; bidx = k0 + 1; }
            if (v2 > best) { best = v2; bidx = k0 + 2; }
            if (v3 > best) { best = v3; bidx = k0 + 3; }
        }

        // ---- combine the wave's 4 segs per j via shfl (disjoint ascending k
        // ranges: tie -> smaller bidx == sequential first-max). No sync.
        {
            float ov = __shfl_xor(best, 16);
            int   oi = __shfl_xor(bidx, 16);
            if (ov > best || (ov == best && oi < bidx)) { best = ov; bidx = oi; }
            ov = __shfl_xor(best, 32);
            oi = __shfl_xor(bidx, 32);
            if (ov > best || (ov == best && oi < bidx)) { best = ov; bidx = oi; }
        }
        if ((tid & 63) < JPB) {                 // one lane per (wave, jj)
            smaxw[wav][jj] = best;
            sidxw[wav][jj] = (unsigned short)bidx;
        }
        __syncthreads();                        // barrier 2: partials visible

        // ---- final 4-deep combine (ascending wave == ascending seg) + publish
        if (tid < JPB) {
            float m = smaxw[0][tid];
            int  mi = sidxw[0][tid];
            #pragma unroll
            for (int ww = 1; ww < 4; ++ww) {
                float v = smaxw[ww][tid];
                if (v > m) { m = v; mi = sidxw[ww][tid]; }
            }
            int jw = j0 + tid;
            // reference quirk: j==0 forced from state 0; prevs[0] (staged by
            // tid 0, wave 0 -- not yet overwritten) is cols[t-1][0].
            float val = (jw == 0) ? (prevs[0] + lat00) : m;
            float out = val + esum_reg;         // one register add -- R3 chain
            __hip_atomic_store((u32*)(cols + (size_t)t * NSTATES) + jw,
                               __float_as_uint(out), __ATOMIC_RELAXED,
                               __HIP_MEMORY_SCOPE_AGENT);
            bptr[(size_t)t * NSTATES + jw] = (unsigned short)mi;
        }

        // ---- post-publish shadow: step t+1's emission slice + serial d-sum
        // (ascending d, bit-order identical to all passing rounds). Sits in
        // the ~2us poll slack. Buffer (t+1)&1 last read at step t-1 => safe.
        if (t + 1 < TT) {
            emis(t + 1, (t + 1) & 1);
            __syncthreads();                    // barrier 3 (in shadow)
            if (tid < JPB) {
                float acc = 0.0f;
                #pragma unroll
                for (int d = 0; d < DD; ++d) acc += elp[(t + 1) & 1][tid][d];
                esum_reg = acc;
            }
        }
        // no fourth barrier: next iteration's prevs staging only overwrites
        // rows whose readers completed before barrier 2; smaxw reuse is
        // ordered by the next iteration's barrier 1.
    }
}

// Double-buffered backtrace: 255 threads stage chunk c+1 from HBM while
// lane 0 chases chunk c through LDS. BTC 24 (96 KB LDS): 171 chunks ->
// ~85 fewer barrier pairs than BTC 16.
#define BTC 24
__global__ void k_backtrace(const float* __restrict__ lastcol,
                            const unsigned short* __restrict__ bptr,
                            int* __restrict__ seq)
{
    __shared__ unsigned short ring[2][BTC][NSTATES];
    __shared__ int s_front;
    const int tid = threadIdx.x;    // 256 threads

    // last = first-max argmax over final column (wave 0)
    if (tid < 64) {
        float best = -__builtin_inff();
        int bi = 0;
        for (int n2 = tid; n2 < NSTATES; n2 += 64) {
            float v = lastcol[n2];
            if (v > best) { best = v; bi = n2; }
        }
        #pragma unroll
        for (int off = 32; off > 0; off >>= 1) {
            float ov = __shfl_xor(best, off);
            int   oi = __shfl_xor(bi, off);
            if (ov > best || (ov == best && oi < bi)) { best = ov; bi = oi; }
        }
        if (tid == 0) { seq[TT] = bi; seq[TT - 1] = bi; s_front = bi; }
    }
    __syncthreads();

    // chunks descend: chunk c covers rows rhi=TT-1-c*BTC .. max(rhi-BTC+1, 1).
    auto stage = [&](int c, int buf, int t0, int stride) {
        int rhi = TT - 1 - c * BTC;
        int rlo = rhi - (BTC - 1); if (rlo < 1) rlo = 1;
        int n4 = (rhi - rlo + 1) * 128;                 // uint4 per chunk
        uint4* dst = (uint4*)&ring[buf][0][0];
        for (int idx = t0; idx < n4; idx += stride) {
            int ro = idx >> 7, wo = idx & 127;
            dst[idx] = ((const uint4*)(bptr + (size_t)(rhi - ro) * NSTATES))[wo];
        }
    };
    const int nc = (TT - 1 + BTC - 1) / BTC;            // 171
    stage(0, 0, tid, 256);
    __syncthreads();
    for (int c = 0; c < nc; ++c) {
        int buf = c & 1;
        if (tid != 0) {
            if (c + 1 < nc) stage(c + 1, buf ^ 1, tid - 1, 255);
        } else {
            int rhi = TT - 1 - c * BTC;
            int rlo = rhi - (BTC - 1); if (rlo < 1) rlo = 1;
            int front = s_front;
            for (int r = rhi; r >= rlo; --r) {
                front = (int)ring[buf][rhi - r][front];
                seq[r - 1] = front;
            }
            s_front = front;
        }
        __syncthreads();
    }
}

extern "C" void kernel_launch(void* const* d_in, const int* in_sizes, int n_in,
                              void* d_out, int out_size, void* d_ws, size_t ws_size,
                              hipStream_t stream) {
    const float* ev    = (const float*)d_in[0];   // [T, D]
    const float* prior = (const float*)d_in[1];   // [N]
    const float* tr    = (const float*)d_in[2];   // [N, N]
    const float* epar  = (const float*)d_in[3];   // [N, D, 2]
    int* seq = (int*)d_out;                       // [T+1]
    char* ws = (char*)d_ws;
    float* cols = (float*)(ws + OFF_COLS);
    unsigned short* bptr = (unsigned short*)(ws + OFF_PTR);
    u32* ready = (u32*)(ws + OFF_PTR);            // bptr row 0 (dead): counter

    hipMemsetAsync(ready, 0, 4, stream);          // zero grid-ready counter
    k_forward<<<FW_BLOCKS, FW_THREADS, 0, stream>>>(tr, ev, epar, prior,
                                                    cols, bptr, ready);
    k_backtrace<<<1, 256, 0, stream>>>(cols + (size_t)(TT - 1) * NSTATES, bptr, seq);
}

// Round 13
// 8677.509 us; speedup vs baseline: 1.6933x; 1.0892x over previous
//
#include <hip/hip_runtime.h>
#include <math.h>

#define NSTATES 1024
#define TT      4096
#define DD      20

#define FW_BLOCKS  64
#define FW_THREADS 256
#define JPB  16      // j per block   (FW_BLOCKS * JPB = NSTATES)
#define NSEG 16      // k segments    (JPB * NSEG = FW_THREADS)
#define KSEG 64      // k per segment (NSEG * KSEG = NSTATES)

#define SENT 0x7FC00000u   // canonical NaN: computed column values are never NaN

// workspace layout (bytes)
//   ws + 0      : ctrl[4]   (u32: [0]=fw ready, [1]=map count, [2]=compose flag)
//   ws + 256    : entries[64] (u32 per-segment entry front)
//   ws + 4096   : maps[64][512] (u32-packed u16 exit maps, 128 KB)
#define OFF_COLS  ((size_t)20 << 20)        // 16 MB per-step columns cols[t*N+j]
#define OFF_PTR   ((size_t)36 << 20)        // 8 MB  u16 backpointers, rows 1..T-1

typedef unsigned int u32;

#define ALD(p) __hip_atomic_load((p), __ATOMIC_RELAXED, __HIP_MEMORY_SCOPE_AGENT)
#define AST(p, v) __hip_atomic_store((p), (v), __ATOMIC_RELAXED, __HIP_MEMORY_SCOPE_AGENT)

// Forward pass: R12 verbatim (best measured: 8612 us dispatch, 2.10 us/step).
__global__ __launch_bounds__(FW_THREADS, 1) void k_forward(
    const float* __restrict__ tr, const float* __restrict__ ev,
    const float* __restrict__ epar, const float* __restrict__ prior,
    float* __restrict__ cols, unsigned short* __restrict__ bptr,
    u32* __restrict__ ready)
{
    // padded [16][68]: row r holds words [r*64, r*64+64) of the prev column.
    __shared__ __align__(16) float prevs[NSEG * 68];
    __shared__ float          smaxw[4][JPB];   // per-wave partials (segs 4w..4w+3)
    __shared__ unsigned short sidxw[4][JPB];
    __shared__ float          elp[2][JPB][DD]; // double-buffered emission log-p
    const int tid  = threadIdx.x;
    const int seg  = tid >> 4;                  // 0..15: k in [seg*64, seg*64+64)
    const int jj   = tid & (JPB - 1);
    const int wav  = tid >> 6;                  // wave id 0..3 (holds segs 4w..4w+3)
    const int j0   = blockIdx.x * JPB;
    const int j    = j0 + jj;

    // ---- prologue A: sentinel-fill this block's slice of cols (256 KB)
    {
        uint4* mine = (uint4*)cols + (size_t)blockIdx.x * (NSTATES * TT / 4 / FW_BLOCKS);
        const uint4 sv = make_uint4(SENT, SENT, SENT, SENT);
        #pragma unroll
        for (int i = 0; i < (NSTATES * TT / 4 / FW_BLOCKS) / FW_THREADS; ++i)
            mine[i * FW_THREADS + tid] = sv;
    }

    // ---- prologue B: lat slice direct from tr (bit-identical to k_logtrans:
    // same logf on the same tr element). lat[j*N+k] = logf(tr[k*N+j]).
    const float lat00 = logf(tr[0]);            // log trans[0][0] (j==0 quirk)
    float4 latr[16];
    #pragma unroll
    for (int u = 0; u < 16; ++u) {
        #pragma unroll
        for (int i = 0; i < 4; ++i) {
            int k = seg * KSEG + u * 4 + i;
            ((float*)&latr[u])[i] = logf(tr[(size_t)k * NSTATES + j]);
        }
    }

    // ---- distributed-emission constants (items: it0 = tid, it1 = tid+256);
    // item -> (jj_e = item/20, d_e = item%20); 320 items cover 16j x 20d.
    const int jj0e = tid / DD, d0e = tid % DD;
    const float m0 = epar[((size_t)(j0 + jj0e) * DD + d0e) * 2 + 0];
    const float s0 = epar[((size_t)(j0 + jj0e) * DD + d0e) * 2 + 1];
    const float coef0 = 1.0f / sqrtf(6.2831853071795864769f * s0);
    const float den0  = 2.0f * (s0 * s0);
    const bool  has1  = (tid + 256) < JPB * DD;     // tid < 64
    const int   it1   = tid + 256;
    const int jj1e = has1 ? it1 / DD : 0, d1e = has1 ? it1 % DD : 0;
    const float m1 = has1 ? epar[((size_t)(j0 + jj1e) * DD + d1e) * 2 + 0] : 0.0f;
    const float s1 = has1 ? epar[((size_t)(j0 + jj1e) * DD + d1e) * 2 + 1] : 1.0f;
    const float coef1 = 1.0f / sqrtf(6.2831853071795864769f * s1);
    const float den1  = 2.0f * (s1 * s1);

    // faithful to reference: p = coef * expf(-num/den); logp = logf(p).
    // -inf (underflow) propagates; never NaN. Verbatim from the verified k_emis.
    auto emis = [&](int t, int buf) {
        float x0  = ev[(size_t)t * DD + d0e];
        float df0 = x0 - m0;
        float num0 = df0 * df0;
        float p0  = coef0 * expf(-num0 / den0);
        elp[buf][jj0e][d0e] = logf(p0);
        if (has1) {
            float x1  = ev[(size_t)t * DD + d1e];
            float df1 = x1 - m1;
            float num1 = df1 * df1;
            float p1  = coef1 * expf(-num1 / den1);
            elp[buf][jj1e][d1e] = logf(p1);
        }
    };

    // ---- prologue C: grid-ready barrier (fill visible -> count -> spin)
    __syncthreads();                            // block's fill issued by all
    if (tid == 0) {
        asm volatile("s_waitcnt vmcnt(0)" ::: "memory");   // fill visible first
        __hip_atomic_fetch_add(ready, 1u, __ATOMIC_RELEASE,
                               __HIP_MEMORY_SCOPE_AGENT);
        while (ALD(ready) < (u32)FW_BLOCKS) __builtin_amdgcn_s_sleep(2);
    }
    __syncthreads();                            // whole grid sentinel-ready

    // thread stages its 4 polled words at padded (row tid>>4, col (tid&15)*4)
    float* dstp = &prevs[(tid >> 4) * 68 + (tid & 15) * 4];
    const float* rowp = &prevs[seg * 68];

    // ---- prologue D: col0 (t=0) and the pipelined esum for t=1 ----
    emis(0, 0);
    __syncthreads();
    if (tid < JPB) {
        float acc = 0.0f;
        #pragma unroll
        for (int d = 0; d < DD; ++d) acc += elp[0][tid][d];   // ascending d
        float c0 = logf(prior[j0 + tid]) + acc;
        AST((u32*)cols + (j0 + tid), __float_as_uint(c0));
    }
    __syncthreads();                            // col0 sum read before buf reuse
    emis(1, 1);
    __syncthreads();
    float esum_reg = 0.0f;
    if (tid < JPB) {
        #pragma unroll
        for (int d = 0; d < DD; ++d) esum_reg += elp[1][tid][d];   // ascending d
    }

    for (int t = 1; t < TT; ++t) {
        // ---- poll previous column: 4 relaxed agent-scope word loads/thread,
        // per-thread exit (the proven protocol).
        const u32* p = (const u32*)(cols + (size_t)(t - 1) * NSTATES) + tid * 4;
        u32 w0, w1, w2, w3;
        for (;;) {
            w0 = ALD(p + 0);
            w1 = ALD(p + 1);
            w2 = ALD(p + 2);
            w3 = ALD(p + 3);
            if (w0 != SENT && w1 != SENT && w2 != SENT && w3 != SENT) break;
            __builtin_amdgcn_s_sleep(1);
        }
        {
            float4 v;
            v.x = __uint_as_float(w0);
            v.y = __uint_as_float(w1);
            v.z = __uint_as_float(w2);
            v.w = __uint_as_float(w3);
            *(float4*)dstp = v;                 // padded b128 store, conflict-free
        }
        __syncthreads();                        // barrier 1: staging visible to all

        // ---- scan this thread's 64 k's for its j: first-max (strict >, asc k)
        float best = -__builtin_inff();
        int bidx = seg * KSEG;
        #pragma unroll
        for (int u = 0; u < 16; ++u) {
            float4 q  = *(const float4*)(rowp + u * 4);   // 16-lane broadcast
            float4 wv = latr[u];
            int k0 = seg * KSEG + u * 4;
            float v0 = q.x + wv.x;
            float v1 = q.y + wv.y;
            float v2 = q.z + wv.z;
            float v3 = q.w + wv.w;
            if (v0 > best) { best = v0; bidx = k0;     }
            if (v1 > best) { best = v1; bidx = k0 + 1; }
            if (v2 > best) { best = v2; bidx = k0 + 2; }
            if (v3 > best) { best = v3; bidx = k0 + 3; }
        }

        // ---- combine the wave's 4 segs per j via shfl (disjoint ascending k
        // ranges: tie -> smaller bidx == sequential first-max). No sync.
        {
            float ov = __shfl_xor(best, 16);
            int   oi = __shfl_xor(bidx, 16);
            if (ov > best || (ov == best && oi < bidx)) { best = ov; bidx = oi; }
            ov = __shfl_xor(best, 32);
            oi = __shfl_xor(bidx, 32);
            if (ov > best || (ov == best && oi < bidx)) { best = ov; bidx = oi; }
        }
        if ((tid & 63) < JPB) {                 // one lane per (wave, jj)
            smaxw[wav][jj] = best;
            sidxw[wav][jj] = (unsigned short)bidx;
        }
        __syncthreads();                        // barrier 2: partials visible

        // ---- final 4-deep combine (ascending wave == ascending seg) + publish
        if (tid < JPB) {
            float m = smaxw[0][tid];
            int  mi = sidxw[0][tid];
            #pragma unroll
            for (int ww = 1; ww < 4; ++ww) {
                float v = smaxw[ww][tid];
                if (v > m) { m = v; mi = sidxw[ww][tid]; }
            }
            int jw = j0 + tid;
            // reference quirk: j==0 forced from state 0; prevs[0] (staged by
            // tid 0, wave 0 -- not yet overwritten) is cols[t-1][0].
            float val = (jw == 0) ? (prevs[0] + lat00) : m;
            float out = val + esum_reg;         // one register add -- R3 chain
            AST((u32*)(cols + (size_t)t * NSTATES) + jw, __float_as_uint(out));
            bptr[(size_t)t * NSTATES + jw] = (unsigned short)mi;
        }

        // ---- post-publish shadow: step t+1's emission slice + serial d-sum
        // (ascending d, bit-order identical to all passing rounds).
        if (t + 1 < TT) {
            emis(t + 1, (t + 1) & 1);
            __syncthreads();                    // barrier 3 (in shadow)
            if (tid < JPB) {
                float acc = 0.0f;
                #pragma unroll
                for (int d = 0; d < DD; ++d) acc += elp[(t + 1) & 1][tid][d];
                esum_reg = acc;
            }
        }
    }
}

// Parallel backtrace via segment transfer-map composition.
//   phase 1: block s stages its 64 bptr rows in LDS and computes exit[v] for
//            all 1024 entry values (4 chases/thread, depth<=64, LDS-latency
//            bound ~4us); publishes the packed map (agent-scope stores).
//   phase 2: block 0 argmaxes the last column (verified first-max code),
//            waits for all 64 maps (counter), serially composes 64 lookups
//            to get each segment's entry front, publishes entries + flag.
//   phase 3: every block replays its own 64-row chase from its entry (lane 0,
//            rows still in LDS) and writes its seq slice.
// Replaces a 4095-step serial chase (~250-350us) with ~35us of parallel work.
#define SEGR 64   // rows per segment; 64 segments x 64 rows = rows 0..4095
__global__ __launch_bounds__(256, 1) void k_backtrace(
    const float* __restrict__ lastcol, const unsigned short* __restrict__ bptr,
    int* __restrict__ seq, u32* __restrict__ ctrl,
    u32* __restrict__ entries, u32* __restrict__ maps)
{
    __shared__ unsigned short rows[SEGR][NSTATES];   // 128 KB
    __shared__ int s_last;
    const int tid = threadIdx.x;    // 256 threads
    const int s   = blockIdx.x;     // 64 segments
    const int lo  = (s == 0) ? 1 : s * SEGR;          // row 0 is never chased
    const int hi  = s * SEGR + SEGR - 1;              // s=63 -> 4095
    const int nrows = hi - lo + 1;

    // ---- stage rows lo..hi (coalesced uint4)
    for (int idx = tid; idx < nrows * 128; idx += 256) {
        int ro = idx >> 7, wo = idx & 127;
        ((uint4*)&rows[ro][0])[wo] =
            ((const uint4*)(bptr + (size_t)(lo + ro) * NSTATES))[wo];
    }
    __syncthreads();

    // ---- phase 1: 4 interleaved chases per thread over all staged rows
    int f0 = tid * 4, f1 = tid * 4 + 1, f2 = tid * 4 + 2, f3 = tid * 4 + 3;
    for (int r = hi; r >= lo; --r) {
        const unsigned short* row = &rows[r - lo][0];
        f0 = row[f0]; f1 = row[f1]; f2 = row[f2]; f3 = row[f3];
    }
    AST(maps + (size_t)s * 512 + 2 * tid,     (u32)f0 | ((u32)f1 << 16));
    AST(maps + (size_t)s * 512 + 2 * tid + 1, (u32)f2 | ((u32)f3 << 16));
    __syncthreads();                 // each wave drains vmcnt before barrier
    if (tid == 0)
        __hip_atomic_fetch_add(ctrl + 1, 1u, __ATOMIC_RELEASE,
                               __HIP_MEMORY_SCOPE_AGENT);

    // ---- phase 2 (block 0): argmax last column, compose maps, publish entries
    if (s == 0) {
        if (tid < 64) {
            float best = -__builtin_inff();
            int bi = 0;
            for (int n2 = tid; n2 < NSTATES; n2 += 64) {
                float v = lastcol[n2];
                if (v > best) { best = v; bi = n2; }
            }
            #pragma unroll
            for (int off = 32; off > 0; off >>= 1) {
                float ov = __shfl_xor(best, off);
                int   oi = __shfl_xor(bi, off);
                if (ov > best || (ov == best && oi < bi)) { best = ov; bi = oi; }
            }
            if (tid == 0) s_last = bi;
        }
        __syncthreads();
        if (tid == 0) {
            while (ALD(ctrl + 1) < 64u) __builtin_amdgcn_s_sleep(2);
            int last = s_last;
            seq[TT] = last; seq[TT - 1] = last;     // source appends twice
            u32 entry = (u32)last;
            for (int ss = 63; ss >= 1; --ss) {      // descending segment order
                AST(entries + ss, entry);
                u32 w = ALD(maps + (size_t)ss * 512 + (entry >> 1));
                entry = (entry & 1) ? (w >> 16) : (w & 0xFFFFu);
            }
            AST(entries + 0, entry);
            asm volatile("s_waitcnt vmcnt(0)" ::: "memory");  // entries first
            AST(ctrl + 2, 1u);                       // compose-done flag
        }
    }

    // ---- phase 3: replay own segment from its entry front (rows still in LDS)
    if (tid == 0) {
        while (ALD(ctrl + 2) == 0u) __builtin_amdgcn_s_sleep(2);
        u32 front = ALD(entries + s);
        for (int r = hi; r >= lo; --r) {
            front = rows[r - lo][front];
            seq[r - 1] = (int)front;
        }
    }
}

extern "C" void kernel_launch(void* const* d_in, const int* in_sizes, int n_in,
                              void* d_out, int out_size, void* d_ws, size_t ws_size,
                              hipStream_t stream) {
    const float* ev    = (const float*)d_in[0];   // [T, D]
    const float* prior = (const float*)d_in[1];   // [N]
    const float* tr    = (const float*)d_in[2];   // [N, N]
    const float* epar  = (const float*)d_in[3];   // [N, D, 2]
    int* seq = (int*)d_out;                       // [T+1]
    char* ws = (char*)d_ws;
    float* cols = (float*)(ws + OFF_COLS);
    unsigned short* bptr = (unsigned short*)(ws + OFF_PTR);
    u32* ctrl    = (u32*)ws;                      // [0]=fw ready [1]=maps [2]=flag
    u32* entries = (u32*)(ws + 256);
    u32* maps    = (u32*)(ws + 4096);

    hipMemsetAsync(ctrl, 0, 16, stream);          // zero control words
    k_forward<<<FW_BLOCKS, FW_THREADS, 0, stream>>>(tr, ev, epar, prior,
                                                    cols, bptr, ctrl);
    k_backtrace<<<64, 256, 0, stream>>>(cols + (size_t)(TT - 1) * NSTATES,
                                        bptr, seq, ctrl, entries, maps);
}

// Round 14
// 8436.327 us; speedup vs baseline: 1.7417x; 1.0286x over previous
//
#include <hip/hip_runtime.h>
#include <math.h>

#define NSTATES 1024
#define TT      4096
#define DD      20

#define FW_BLOCKS  64
#define FW_THREADS 256
#define JPB  16      // j per block   (FW_BLOCKS * JPB = NSTATES)
#define NSEG 16      // k segments    (JPB * NSEG = FW_THREADS)
#define KSEG 64      // k per segment (NSEG * KSEG = NSTATES)

#define SENT 0x7FC00000u   // canonical NaN: computed column values are never NaN

// workspace layout (bytes)
//   ws + 0      : ctrl[4]   (u32: [0]=fw ready, [1]=map count, [2]=compose flag)
//   ws + 256    : entries[64] (u32 per-segment entry front)
//   ws + 4096   : maps[64][512] (u32-packed u16 exit maps, 128 KB)
#define OFF_COLS  ((size_t)20 << 20)        // 16 MB per-step columns cols[t*N+j]
#define OFF_PTR   ((size_t)36 << 20)        // 8 MB  u16 backpointers, rows 1..T-1

typedef unsigned int u32;
typedef u32 u32x4 __attribute__((ext_vector_type(4)));

#define ALD(p) __hip_atomic_load((p), __ATOMIC_RELAXED, __HIP_MEMORY_SCOPE_AGENT)
#define AST(p, v) __hip_atomic_store((p), (v), __ATOMIC_RELAXED, __HIP_MEMORY_SCOPE_AGENT)

// Forward pass: R12/R13 structure verbatim except the poll, which now uses
// ONE plain (non-atomic) global_load_dwordx4 sc1 per thread per sweep
// instead of 4 agent-scope atomic word loads.
//   Mechanism: atomic loads are processed serially by the LLC atomic units;
//   256 atomic pollers per column line per sweep add ~1-2K cycles of queueing
//   to every poll RTT (the unexplained ~2500cy of the 5040cy step). Plain
//   sc1 loads are LLC-served reads with no atomic serialization.
//   Safety: sc1 freshness proven in R5/R6 (both passed with sc1 sweeps as
//   the exit path); 32-try ALD fallback keeps staleness slow-but-correct.
__global__ __launch_bounds__(FW_THREADS, 1) void k_forward(
    const float* __restrict__ tr, const float* __restrict__ ev,
    const float* __restrict__ epar, const float* __restrict__ prior,
    float* __restrict__ cols, unsigned short* __restrict__ bptr,
    u32* __restrict__ ready)
{
    // padded [16][68]: row r holds words [r*64, r*64+64) of the prev column.
    __shared__ __align__(16) float prevs[NSEG * 68];
    __shared__ float          smaxw[4][JPB];   // per-wave partials (segs 4w..4w+3)
    __shared__ unsigned short sidxw[4][JPB];
    __shared__ float          elp[2][JPB][DD]; // double-buffered emission log-p
    const int tid  = threadIdx.x;
    const int seg  = tid >> 4;                  // 0..15: k in [seg*64, seg*64+64)
    const int jj   = tid & (JPB - 1);
    const int wav  = tid >> 6;                  // wave id 0..3 (holds segs 4w..4w+3)
    const int j0   = blockIdx.x * JPB;
    const int j    = j0 + jj;

    // ---- prologue A: sentinel-fill this block's slice of cols (256 KB)
    {
        uint4* mine = (uint4*)cols + (size_t)blockIdx.x * (NSTATES * TT / 4 / FW_BLOCKS);
        const uint4 sv = make_uint4(SENT, SENT, SENT, SENT);
        #pragma unroll
        for (int i = 0; i < (NSTATES * TT / 4 / FW_BLOCKS) / FW_THREADS; ++i)
            mine[i * FW_THREADS + tid] = sv;
    }

    // ---- prologue B: lat slice direct from tr (bit-identical to k_logtrans:
    // same logf on the same tr element). lat[j*N+k] = logf(tr[k*N+j]).
    const float lat00 = logf(tr[0]);            // log trans[0][0] (j==0 quirk)
    float4 latr[16];
    #pragma unroll
    for (int u = 0; u < 16; ++u) {
        #pragma unroll
        for (int i = 0; i < 4; ++i) {
            int k = seg * KSEG + u * 4 + i;
            ((float*)&latr[u])[i] = logf(tr[(size_t)k * NSTATES + j]);
        }
    }

    // ---- distributed-emission constants (items: it0 = tid, it1 = tid+256);
    // item -> (jj_e = item/20, d_e = item%20); 320 items cover 16j x 20d.
    const int jj0e = tid / DD, d0e = tid % DD;
    const float m0 = epar[((size_t)(j0 + jj0e) * DD + d0e) * 2 + 0];
    const float s0 = epar[((size_t)(j0 + jj0e) * DD + d0e) * 2 + 1];
    const float coef0 = 1.0f / sqrtf(6.2831853071795864769f * s0);
    const float den0  = 2.0f * (s0 * s0);
    const bool  has1  = (tid + 256) < JPB * DD;     // tid < 64
    const int   it1   = tid + 256;
    const int jj1e = has1 ? it1 / DD : 0, d1e = has1 ? it1 % DD : 0;
    const float m1 = has1 ? epar[((size_t)(j0 + jj1e) * DD + d1e) * 2 + 0] : 0.0f;
    const float s1 = has1 ? epar[((size_t)(j0 + jj1e) * DD + d1e) * 2 + 1] : 1.0f;
    const float coef1 = 1.0f / sqrtf(6.2831853071795864769f * s1);
    const float den1  = 2.0f * (s1 * s1);

    // faithful to reference: p = coef * expf(-num/den); logp = logf(p).
    // -inf (underflow) propagates; never NaN. Verbatim from the verified k_emis.
    auto emis = [&](int t, int buf) {
        float x0  = ev[(size_t)t * DD + d0e];
        float df0 = x0 - m0;
        float num0 = df0 * df0;
        float p0  = coef0 * expf(-num0 / den0);
        elp[buf][jj0e][d0e] = logf(p0);
        if (has1) {
            float x1  = ev[(size_t)t * DD + d1e];
            float df1 = x1 - m1;
            float num1 = df1 * df1;
            float p1  = coef1 * expf(-num1 / den1);
            elp[buf][jj1e][d1e] = logf(p1);
        }
    };

    // ---- prologue C: grid-ready barrier (fill visible -> count -> spin)
    __syncthreads();                            // block's fill issued by all
    if (tid == 0) {
        asm volatile("s_waitcnt vmcnt(0)" ::: "memory");   // fill visible first
        __hip_atomic_fetch_add(ready, 1u, __ATOMIC_RELEASE,
                               __HIP_MEMORY_SCOPE_AGENT);
        while (ALD(ready) < (u32)FW_BLOCKS) __builtin_amdgcn_s_sleep(2);
    }
    __syncthreads();                            // whole grid sentinel-ready

    // thread stages its 4 polled words at padded (row tid>>4, col (tid&15)*4)
    float* dstp = &prevs[(tid >> 4) * 68 + (tid & 15) * 4];
    const float* rowp = &prevs[seg * 68];

    // ---- prologue D: col0 (t=0) and the pipelined esum for t=1 ----
    emis(0, 0);
    __syncthreads();
    if (tid < JPB) {
        float acc = 0.0f;
        #pragma unroll
        for (int d = 0; d < DD; ++d) acc += elp[0][tid][d];   // ascending d
        float c0 = logf(prior[j0 + tid]) + acc;
        AST((u32*)cols + (j0 + tid), __float_as_uint(c0));
    }
    __syncthreads();                            // col0 sum read before buf reuse
    emis(1, 1);
    __syncthreads();
    float esum_reg = 0.0f;
    if (tid < JPB) {
        #pragma unroll
        for (int d = 0; d < DD; ++d) esum_reg += elp[1][tid][d];   // ascending d
    }

    for (int t = 1; t < TT; ++t) {
        // ---- poll previous column: ONE plain dwordx4 sc1 sweep per thread
        // (non-atomic: no LLC atomic-unit serialization), s_sleep backoff,
        // 32-try agent-scope ALD fallback (proven coherent) for hang-safety.
        const u32* p = (const u32*)(cols + (size_t)(t - 1) * NSTATES) + tid * 4;
        u32x4 A;
        int tries = 0;
        for (;;) {
            asm volatile(
                "global_load_dwordx4 %0, %1, off sc1\n\t"
                "s_waitcnt vmcnt(0)"
                : "=&v"(A) : "v"(p) : "memory");
            if (A.x != SENT && A.y != SENT && A.z != SENT && A.w != SENT) break;
            if (++tries >= 32) {
                u32 a0 = ALD(p + 0), a1 = ALD(p + 1), a2 = ALD(p + 2), a3 = ALD(p + 3);
                if (a0 != SENT && a1 != SENT && a2 != SENT && a3 != SENT) {
                    A.x = a0; A.y = a1; A.z = a2; A.w = a3;
                    break;
                }
                tries = 0;
            }
            __builtin_amdgcn_s_sleep(1);
        }
        {
            float4 v;
            v.x = __uint_as_float(A.x);
            v.y = __uint_as_float(A.y);
            v.z = __uint_as_float(A.z);
            v.w = __uint_as_float(A.w);
            *(float4*)dstp = v;                 // padded b128 store, conflict-free
        }
        __syncthreads();                        // barrier 1: staging visible to all

        // ---- scan this thread's 64 k's for its j: first-max (strict >, asc k)
        float best = -__builtin_inff();
        int bidx = seg * KSEG;
        #pragma unroll
        for (int u = 0; u < 16; ++u) {
            float4 q  = *(const float4*)(rowp + u * 4);   // 16-lane broadcast
            float4 wv = latr[u];
            int k0 = seg * KSEG + u * 4;
            float v0 = q.x + wv.x;
            float v1 = q.y + wv.y;
            float v2 = q.z + wv.z;
            float v3 = q.w + wv.w;
            if (v0 > best) { best = v0; bidx = k0;     }
            if (v1 > best) { best = v1; bidx = k0 + 1; }
            if (v2 > best) { best = v2; bidx = k0 + 2; }
            if (v3 > best) { best = v3; bidx = k0 + 3; }
        }

        // ---- combine the wave's 4 segs per j via shfl (disjoint ascending k
        // ranges: tie -> smaller bidx == sequential first-max). No sync.
        {
            float ov = __shfl_xor(best, 16);
            int   oi = __shfl_xor(bidx, 16);
            if (ov > best || (ov == best && oi < bidx)) { best = ov; bidx = oi; }
            ov = __shfl_xor(best, 32);
            oi = __shfl_xor(bidx, 32);
            if (ov > best || (ov == best && oi < bidx)) { best = ov; bidx = oi; }
        }
        if ((tid & 63) < JPB) {                 // one lane per (wave, jj)
            smaxw[wav][jj] = best;
            sidxw[wav][jj] = (unsigned short)bidx;
        }
        __syncthreads();                        // barrier 2: partials visible

        // ---- final 4-deep combine (ascending wave == ascending seg) + publish
        if (tid < JPB) {
            float m = smaxw[0][tid];
            int  mi = sidxw[0][tid];
            #pragma unroll
            for (int ww = 1; ww < 4; ++ww) {
                float v = smaxw[ww][tid];
                if (v > m) { m = v; mi = sidxw[ww][tid]; }
            }
            int jw = j0 + tid;
            // reference quirk: j==0 forced from state 0; prevs[0] (staged by
            // tid 0, wave 0 -- not yet overwritten) is cols[t-1][0].
            float val = (jw == 0) ? (prevs[0] + lat00) : m;
            float out = val + esum_reg;         // one register add -- R3 chain
            AST((u32*)(cols + (size_t)t * NSTATES) + jw, __float_as_uint(out));
            bptr[(size_t)t * NSTATES + jw] = (unsigned short)mi;
        }

        // ---- post-publish shadow: step t+1's emission slice + serial d-sum
        // (ascending d, bit-order identical to all passing rounds).
        if (t + 1 < TT) {
            emis(t + 1, (t + 1) & 1);
            __syncthreads();                    // barrier 3 (in shadow)
            if (tid < JPB) {
                float acc = 0.0f;
                #pragma unroll
                for (int d = 0; d < DD; ++d) acc += elp[(t + 1) & 1][tid][d];
                esum_reg = acc;
            }
        }
    }
}

// Parallel backtrace via segment transfer-map composition (verified R13).
#define SEGR 64   // rows per segment; 64 segments x 64 rows = rows 0..4095
__global__ __launch_bounds__(256, 1) void k_backtrace(
    const float* __restrict__ lastcol, const unsigned short* __restrict__ bptr,
    int* __restrict__ seq, u32* __restrict__ ctrl,
    u32* __restrict__ entries, u32* __restrict__ maps)
{
    __shared__ unsigned short rows[SEGR][NSTATES];   // 128 KB
    __shared__ int s_last;
    const int tid = threadIdx.x;    // 256 threads
    const int s   = blockIdx.x;     // 64 segments
    const int lo  = (s == 0) ? 1 : s * SEGR;          // row 0 is never chased
    const int hi  = s * SEGR + SEGR - 1;              // s=63 -> 4095
    const int nrows = hi - lo + 1;

    // ---- stage rows lo..hi (coalesced uint4)
    for (int idx = tid; idx < nrows * 128; idx += 256) {
        int ro = idx >> 7, wo = idx & 127;
        ((uint4*)&rows[ro][0])[wo] =
            ((const uint4*)(bptr + (size_t)(lo + ro) * NSTATES))[wo];
    }
    __syncthreads();

    // ---- phase 1: 4 interleaved chases per thread over all staged rows
    int f0 = tid * 4, f1 = tid * 4 + 1, f2 = tid * 4 + 2, f3 = tid * 4 + 3;
    for (int r = hi; r >= lo; --r) {
        const unsigned short* row = &rows[r - lo][0];
        f0 = row[f0]; f1 = row[f1]; f2 = row[f2]; f3 = row[f3];
    }
    AST(maps + (size_t)s * 512 + 2 * tid,     (u32)f0 | ((u32)f1 << 16));
    AST(maps + (size_t)s * 512 + 2 * tid + 1, (u32)f2 | ((u32)f3 << 16));
    __syncthreads();                 // each wave drains vmcnt before barrier
    if (tid == 0)
        __hip_atomic_fetch_add(ctrl + 1, 1u, __ATOMIC_RELEASE,
                               __HIP_MEMORY_SCOPE_AGENT);

    // ---- phase 2 (block 0): argmax last column, compose maps, publish entries
    if (s == 0) {
        if (tid < 64) {
            float best = -__builtin_inff();
            int bi = 0;
            for (int n2 = tid; n2 < NSTATES; n2 += 64) {
                float v = lastcol[n2];
                if (v > best) { best = v; bi = n2; }
            }
            #pragma unroll
            for (int off = 32; off > 0; off >>= 1) {
                float ov = __shfl_xor(best, off);
                int   oi = __shfl_xor(bi, off);
                if (ov > best || (ov == best && oi < bi)) { best = ov; bi = oi; }
            }
            if (tid == 0) s_last = bi;
        }
        __syncthreads();
        if (tid == 0) {
            while (ALD(ctrl + 1) < 64u) __builtin_amdgcn_s_sleep(2);
            int last = s_last;
            seq[TT] = last; seq[TT - 1] = last;     // source appends twice
            u32 entry = (u32)last;
            for (int ss = 63; ss >= 1; --ss) {      // descending segment order
                AST(entries + ss, entry);
                u32 w = ALD(maps + (size_t)ss * 512 + (entry >> 1));
                entry = (entry & 1) ? (w >> 16) : (w & 0xFFFFu);
            }
            AST(entries + 0, entry);
            asm volatile("s_waitcnt vmcnt(0)" ::: "memory");  // entries first
            AST(ctrl + 2, 1u);                       // compose-done flag
        }
    }

    // ---- phase 3: replay own segment from its entry front (rows still in LDS)
    if (tid == 0) {
        while (ALD(ctrl + 2) == 0u) __builtin_amdgcn_s_sleep(2);
        u32 front = ALD(entries + s);
        for (int r = hi; r >= lo; --r) {
            front = rows[r - lo][front];
            seq[r - 1] = (int)front;
        }
    }
}

extern "C" void kernel_launch(void* const* d_in, const int* in_sizes, int n_in,
                              void* d_out, int out_size, void* d_ws, size_t ws_size,
                              hipStream_t stream) {
    const float* ev    = (const float*)d_in[0];   // [T, D]
    const float* prior = (const float*)d_in[1];   // [N]
    const float* tr    = (const float*)d_in[2];   // [N, N]
    const float* epar  = (const float*)d_in[3];   // [N, D, 2]
    int* seq = (int*)d_out;                       // [T+1]
    char* ws = (char*)d_ws;
    float* cols = (float*)(ws + OFF_COLS);
    unsigned short* bptr = (unsigned short*)(ws + OFF_PTR);
    u32* ctrl    = (u32*)ws;                      // [0]=fw ready [1]=maps [2]=flag
    u32* entries = (u32*)(ws + 256);
    u32* maps    = (u32*)(ws + 4096);

    hipMemsetAsync(ctrl, 0, 16, stream);          // zero control words
    k_forward<<<FW_BLOCKS, FW_THREADS, 0, stream>>>(tr, ev, epar, prior,
                                                    cols, bptr, ctrl);
    k_backtrace<<<64, 256, 0, stream>>>(cols + (size_t)(TT - 1) * NSTATES,
                                        bptr, seq, ctrl, entries, maps);
}

// Round 15
// 8208.521 us; speedup vs baseline: 1.7900x; 1.0278x over previous
//
#include <hip/hip_runtime.h>
#include <math.h>

#define NSTATES 1024
#define TT      4096
#define DD      20

#define FW_BLOCKS  64
#define FW_THREADS 256
#define JPB  16      // j per block   (FW_BLOCKS * JPB = NSTATES)
#define NSEG 16      // k segments    (JPB * NSEG = FW_THREADS)
#define KSEG 64      // k per segment (NSEG * KSEG = NSTATES)

#define SENT 0x7FC00000u   // canonical NaN: computed column values are never NaN

// workspace layout (bytes)
//   ws + 0      : ctrl[4]   (u32: [0]=fw ready, [1]=map count, [2]=compose flag)
//   ws + 256    : entries[64] (u32 per-segment entry front)
//   ws + 4096   : maps[64][512] (u32-packed u16 exit maps, 128 KB)
#define OFF_COLS  ((size_t)20 << 20)        // 16 MB per-step columns cols[t*N+j]
#define OFF_PTR   ((size_t)36 << 20)        // 8 MB  u16 backpointers, rows 1..T-1

typedef unsigned int u32;
typedef u32 u32x4 __attribute__((ext_vector_type(4)));

#define ALD(p) __hip_atomic_load((p), __ATOMIC_RELAXED, __HIP_MEMORY_SCOPE_AGENT)
#define AST(p, v) __hip_atomic_store((p), (v), __ATOMIC_RELAXED, __HIP_MEMORY_SCOPE_AGENT)

// Forward pass: R14 verbatim except BARRIER 1 IS REMOVED.
//   Justification: staging and scanning of prevs row r are done by the SAME
//   16 threads (tid>>4 == r), all within one wave. Same-wave LDS ops are
//   processed in order, so the scan's ds_reads see the staging ds_write
//   without a block barrier; lgkmcnt(0)+sched_barrier(0) only fences the
//   compiler (pattern proven correct in this session's R2 kernel). The other
//   prevs read (j==0 quirk, prevs[0] after barrier 2) is tid 0 reading its
//   own program-ordered store. smaxw/elp anti-deps are covered by barriers
//   2 and 3. Removes ~100-300cy of barrier+wave-skew from the serial chain
//   and lets each wave scan as soon as its own poll lands.
__global__ __launch_bounds__(FW_THREADS, 1) void k_forward(
    const float* __restrict__ tr, const float* __restrict__ ev,
    const float* __restrict__ epar, const float* __restrict__ prior,
    float* __restrict__ cols, unsigned short* __restrict__ bptr,
    u32* __restrict__ ready)
{
    // padded [16][68]: row r holds words [r*64, r*64+64) of the prev column.
    __shared__ __align__(16) float prevs[NSEG * 68];
    __shared__ float          smaxw[4][JPB];   // per-wave partials (segs 4w..4w+3)
    __shared__ unsigned short sidxw[4][JPB];
    __shared__ float          elp[2][JPB][DD]; // double-buffered emission log-p
    const int tid  = threadIdx.x;
    const int seg  = tid >> 4;                  // 0..15: k in [seg*64, seg*64+64)
    const int jj   = tid & (JPB - 1);
    const int wav  = tid >> 6;                  // wave id 0..3 (holds segs 4w..4w+3)
    const int j0   = blockIdx.x * JPB;
    const int j    = j0 + jj;

    // ---- prologue A: sentinel-fill this block's slice of cols (256 KB)
    {
        uint4* mine = (uint4*)cols + (size_t)blockIdx.x * (NSTATES * TT / 4 / FW_BLOCKS);
        const uint4 sv = make_uint4(SENT, SENT, SENT, SENT);
        #pragma unroll
        for (int i = 0; i < (NSTATES * TT / 4 / FW_BLOCKS) / FW_THREADS; ++i)
            mine[i * FW_THREADS + tid] = sv;
    }

    // ---- prologue B: lat slice direct from tr (bit-identical to k_logtrans:
    // same logf on the same tr element). lat[j*N+k] = logf(tr[k*N+j]).
    const float lat00 = logf(tr[0]);            // log trans[0][0] (j==0 quirk)
    float4 latr[16];
    #pragma unroll
    for (int u = 0; u < 16; ++u) {
        #pragma unroll
        for (int i = 0; i < 4; ++i) {
            int k = seg * KSEG + u * 4 + i;
            ((float*)&latr[u])[i] = logf(tr[(size_t)k * NSTATES + j]);
        }
    }

    // ---- distributed-emission constants (items: it0 = tid, it1 = tid+256);
    // item -> (jj_e = item/20, d_e = item%20); 320 items cover 16j x 20d.
    const int jj0e = tid / DD, d0e = tid % DD;
    const float m0 = epar[((size_t)(j0 + jj0e) * DD + d0e) * 2 + 0];
    const float s0 = epar[((size_t)(j0 + jj0e) * DD + d0e) * 2 + 1];
    const float coef0 = 1.0f / sqrtf(6.2831853071795864769f * s0);
    const float den0  = 2.0f * (s0 * s0);
    const bool  has1  = (tid + 256) < JPB * DD;     // tid < 64
    const int   it1   = tid + 256;
    const int jj1e = has1 ? it1 / DD : 0, d1e = has1 ? it1 % DD : 0;
    const float m1 = has1 ? epar[((size_t)(j0 + jj1e) * DD + d1e) * 2 + 0] : 0.0f;
    const float s1 = has1 ? epar[((size_t)(j0 + jj1e) * DD + d1e) * 2 + 1] : 1.0f;
    const float coef1 = 1.0f / sqrtf(6.2831853071795864769f * s1);
    const float den1  = 2.0f * (s1 * s1);

    // faithful to reference: p = coef * expf(-num/den); logp = logf(p).
    // -inf (underflow) propagates; never NaN. Verbatim from the verified k_emis.
    auto emis = [&](int t, int buf) {
        float x0  = ev[(size_t)t * DD + d0e];
        float df0 = x0 - m0;
        float num0 = df0 * df0;
        float p0  = coef0 * expf(-num0 / den0);
        elp[buf][jj0e][d0e] = logf(p0);
        if (has1) {
            float x1  = ev[(size_t)t * DD + d1e];
            float df1 = x1 - m1;
            float num1 = df1 * df1;
            float p1  = coef1 * expf(-num1 / den1);
            elp[buf][jj1e][d1e] = logf(p1);
        }
    };

    // ---- prologue C: grid-ready barrier (fill visible -> count -> spin)
    __syncthreads();                            // block's fill issued by all
    if (tid == 0) {
        asm volatile("s_waitcnt vmcnt(0)" ::: "memory");   // fill visible first
        __hip_atomic_fetch_add(ready, 1u, __ATOMIC_RELEASE,
                               __HIP_MEMORY_SCOPE_AGENT);
        while (ALD(ready) < (u32)FW_BLOCKS) __builtin_amdgcn_s_sleep(2);
    }
    __syncthreads();                            // whole grid sentinel-ready

    // thread stages its 4 polled words at padded (row tid>>4, col (tid&15)*4)
    float* dstp = &prevs[(tid >> 4) * 68 + (tid & 15) * 4];
    const float* rowp = &prevs[seg * 68];

    // ---- prologue D: col0 (t=0) and the pipelined esum for t=1 ----
    emis(0, 0);
    __syncthreads();
    if (tid < JPB) {
        float acc = 0.0f;
        #pragma unroll
        for (int d = 0; d < DD; ++d) acc += elp[0][tid][d];   // ascending d
        float c0 = logf(prior[j0 + tid]) + acc;
        AST((u32*)cols + (j0 + tid), __float_as_uint(c0));
    }
    __syncthreads();                            // col0 sum read before buf reuse
    emis(1, 1);
    __syncthreads();
    float esum_reg = 0.0f;
    if (tid < JPB) {
        #pragma unroll
        for (int d = 0; d < DD; ++d) esum_reg += elp[1][tid][d];   // ascending d
    }

    for (int t = 1; t < TT; ++t) {
        // ---- poll previous column: ONE plain dwordx4 sc1 sweep per thread
        // (R14, proven), s_sleep backoff, 32-try ALD fallback for hang-safety.
        const u32* p = (const u32*)(cols + (size_t)(t - 1) * NSTATES) + tid * 4;
        u32x4 A;
        int tries = 0;
        for (;;) {
            asm volatile(
                "global_load_dwordx4 %0, %1, off sc1\n\t"
                "s_waitcnt vmcnt(0)"
                : "=&v"(A) : "v"(p) : "memory");
            if (A.x != SENT && A.y != SENT && A.z != SENT && A.w != SENT) break;
            if (++tries >= 32) {
                u32 a0 = ALD(p + 0), a1 = ALD(p + 1), a2 = ALD(p + 2), a3 = ALD(p + 3);
                if (a0 != SENT && a1 != SENT && a2 != SENT && a3 != SENT) {
                    A.x = a0; A.y = a1; A.z = a2; A.w = a3;
                    break;
                }
                tries = 0;
            }
            __builtin_amdgcn_s_sleep(1);
        }
        {
            float4 v;
            v.x = __uint_as_float(A.x);
            v.y = __uint_as_float(A.y);
            v.z = __uint_as_float(A.z);
            v.w = __uint_as_float(A.w);
            *(float4*)dstp = v;                 // padded b128 store, conflict-free
        }
        // barrier 1 REMOVED: row r's stagers == row r's readers (same wave);
        // same-wave LDS pipe is in-order. Fence only stops compiler hoisting
        // the dependent ds_reads above the staging write (rule #18; R2-proven).
        asm volatile("s_waitcnt lgkmcnt(0)" ::: "memory");
        __builtin_amdgcn_sched_barrier(0);

        // ---- scan this thread's 64 k's for its j: first-max (strict >, asc k)
        float best = -__builtin_inff();
        int bidx = seg * KSEG;
        #pragma unroll
        for (int u = 0; u < 16; ++u) {
            float4 q  = *(const float4*)(rowp + u * 4);   // 16-lane broadcast
            float4 wv = latr[u];
            int k0 = seg * KSEG + u * 4;
            float v0 = q.x + wv.x;
            float v1 = q.y + wv.y;
            float v2 = q.z + wv.z;
            float v3 = q.w + wv.w;
            if (v0 > best) { best = v0; bidx = k0;     }
            if (v1 > best) { best = v1; bidx = k0 + 1; }
            if (v2 > best) { best = v2; bidx = k0 + 2; }
            if (v3 > best) { best = v3; bidx = k0 + 3; }
        }

        // ---- combine the wave's 4 segs per j via shfl (disjoint ascending k
        // ranges: tie -> smaller bidx == sequential first-max). No sync.
        {
            float ov = __shfl_xor(best, 16);
            int   oi = __shfl_xor(bidx, 16);
            if (ov > best || (ov == best && oi < bidx)) { best = ov; bidx = oi; }
            ov = __shfl_xor(best, 32);
            oi = __shfl_xor(bidx, 32);
            if (ov > best || (ov == best && oi < bidx)) { best = ov; bidx = oi; }
        }
        if ((tid & 63) < JPB) {                 // one lane per (wave, jj)
            smaxw[wav][jj] = best;
            sidxw[wav][jj] = (unsigned short)bidx;
        }
        __syncthreads();                        // barrier 2: partials visible

        // ---- final 4-deep combine (ascending wave == ascending seg) + publish
        if (tid < JPB) {
            float m = smaxw[0][tid];
            int  mi = sidxw[0][tid];
            #pragma unroll
            for (int ww = 1; ww < 4; ++ww) {
                float v = smaxw[ww][tid];
                if (v > m) { m = v; mi = sidxw[ww][tid]; }
            }
            int jw = j0 + tid;
            // reference quirk: j==0 forced from state 0; prevs[0] (staged by
            // tid 0 itself, program-ordered) is cols[t-1][0].
            float val = (jw == 0) ? (prevs[0] + lat00) : m;
            float out = val + esum_reg;         // one register add -- R3 chain
            AST((u32*)(cols + (size_t)t * NSTATES) + jw, __float_as_uint(out));
            bptr[(size_t)t * NSTATES + jw] = (unsigned short)mi;
        }

        // ---- post-publish shadow: step t+1's emission slice + serial d-sum
        // (ascending d, bit-order identical to all passing rounds).
        if (t + 1 < TT) {
            emis(t + 1, (t + 1) & 1);
            __syncthreads();                    // barrier 3 (in shadow)
            if (tid < JPB) {
                float acc = 0.0f;
                #pragma unroll
                for (int d = 0; d < DD; ++d) acc += elp[(t + 1) & 1][tid][d];
                esum_reg = acc;
            }
        }
    }
}

// Parallel backtrace via segment transfer-map composition (verified R13/R14).
#define SEGR 64   // rows per segment; 64 segments x 64 rows = rows 0..4095
__global__ __launch_bounds__(256, 1) void k_backtrace(
    const float* __restrict__ lastcol, const unsigned short* __restrict__ bptr,
    int* __restrict__ seq, u32* __restrict__ ctrl,
    u32* __restrict__ entries, u32* __restrict__ maps)
{
    __shared__ unsigned short rows[SEGR][NSTATES];   // 128 KB
    __shared__ int s_last;
    const int tid = threadIdx.x;    // 256 threads
    const int s   = blockIdx.x;     // 64 segments
    const int lo  = (s == 0) ? 1 : s * SEGR;          // row 0 is never chased
    const int hi  = s * SEGR + SEGR - 1;              // s=63 -> 4095
    const int nrows = hi - lo + 1;

    // ---- stage rows lo..hi (coalesced uint4)
    for (int idx = tid; idx < nrows * 128; idx += 256) {
        int ro = idx >> 7, wo = idx & 127;
        ((uint4*)&rows[ro][0])[wo] =
            ((const uint4*)(bptr + (size_t)(lo + ro) * NSTATES))[wo];
    }
    __syncthreads();

    // ---- phase 1: 4 interleaved chases per thread over all staged rows
    int f0 = tid * 4, f1 = tid * 4 + 1, f2 = tid * 4 + 2, f3 = tid * 4 + 3;
    for (int r = hi; r >= lo; --r) {
        const unsigned short* row = &rows[r - lo][0];
        f0 = row[f0]; f1 = row[f1]; f2 = row[f2]; f3 = row[f3];
    }
    AST(maps + (size_t)s * 512 + 2 * tid,     (u32)f0 | ((u32)f1 << 16));
    AST(maps + (size_t)s * 512 + 2 * tid + 1, (u32)f2 | ((u32)f3 << 16));
    __syncthreads();                 // each wave drains vmcnt before barrier
    if (tid == 0)
        __hip_atomic_fetch_add(ctrl + 1, 1u, __ATOMIC_RELEASE,
                               __HIP_MEMORY_SCOPE_AGENT);

    // ---- phase 2 (block 0): argmax last column, compose maps, publish entries
    if (s == 0) {
        if (tid < 64) {
            float best = -__builtin_inff();
            int bi = 0;
            for (int n2 = tid; n2 < NSTATES; n2 += 64) {
                float v = lastcol[n2];
                if (v > best) { best = v; bi = n2; }
            }
            #pragma unroll
            for (int off = 32; off > 0; off >>= 1) {
                float ov = __shfl_xor(best, off);
                int   oi = __shfl_xor(bi, off);
                if (ov > best || (ov == best && oi < bi)) { best = ov; bi = oi; }
            }
            if (tid == 0) s_last = bi;
        }
        __syncthreads();
        if (tid == 0) {
            while (ALD(ctrl + 1) < 64u) __builtin_amdgcn_s_sleep(2);
            int last = s_last;
            seq[TT] = last; seq[TT - 1] = last;     // source appends twice
            u32 entry = (u32)last;
            for (int ss = 63; ss >= 1; --ss) {      // descending segment order
                AST(entries + ss, entry);
                u32 w = ALD(maps + (size_t)ss * 512 + (entry >> 1));
                entry = (entry & 1) ? (w >> 16) : (w & 0xFFFFu);
            }
            AST(entries + 0, entry);
            asm volatile("s_waitcnt vmcnt(0)" ::: "memory");  // entries first
            AST(ctrl + 2, 1u);                       // compose-done flag
        }
    }

    // ---- phase 3: replay own segment from its entry front (rows still in LDS)
    if (tid == 0) {
        while (ALD(ctrl + 2) == 0u) __builtin_amdgcn_s_sleep(2);
        u32 front = ALD(entries + s);
        for (int r = hi; r >= lo; --r) {
            front = rows[r - lo][front];
            seq[r - 1] = (int)front;
        }
    }
}

extern "C" void kernel_launch(void* const* d_in, const int* in_sizes, int n_in,
                              void* d_out, int out_size, void* d_ws, size_t ws_size,
                              hipStream_t stream) {
    const float* ev    = (const float*)d_in[0];   // [T, D]
    const float* prior = (const float*)d_in[1];   // [N]
    const float* tr    = (const float*)d_in[2];   // [N, N]
    const float* epar  = (const float*)d_in[3];   // [N, D, 2]
    int* seq = (int*)d_out;                       // [T+1]
    char* ws = (char*)d_ws;
    float* cols = (float*)(ws + OFF_COLS);
    unsigned short* bptr = (unsigned short*)(ws + OFF_PTR);
    u32* ctrl    = (u32*)ws;                      // [0]=fw ready [1]=maps [2]=flag
    u32* entries = (u32*)(ws + 256);
    u32* maps    = (u32*)(ws + 4096);

    hipMemsetAsync(ctrl, 0, 16, stream);          // zero control words
    k_forward<<<FW_BLOCKS, FW_THREADS, 0, stream>>>(tr, ev, epar, prior,
                                                    cols, bptr, ctrl);
    k_backtrace<<<64, 256, 0, stream>>>(cols + (size_t)(TT - 1) * NSTATES,
                                        bptr, seq, ctrl, entries, maps);
}